// Round 7
// baseline (221.086 us; speedup 1.0000x reference)
//
#include <hip/hip_runtime.h>
#include <hip/hip_bf16.h>
#include <math.h>

// Polynomial feature map: Xp = X @ P; out = [bias | Xp | Xp^2 | Xp^3 | pairs | sqrt(|Xp|+eps)]
// X: [16384, 2048] f32, P: [2048, 512] f32, out: [16384, 2561] f32.
// pairs (triu k=1, first 512): c<511 -> Xp[:,0]*Xp[:,c+1]; c==511 -> Xp[:,1]*Xp[:,2]
//
// Path: prep_b (P -> Bt bf16 [512][2048] in ws, L2-resident) ; gemm7 (NO LDS, NO
// barriers: per-wave direct-to-register fragments from L2, full-N tile, static 2-slot
// prefetch) writes p1 ; epi_k expands remaining regions reading p1 back (L2/L3-hot).

typedef __attribute__((ext_vector_type(4))) float f32x4;
typedef __attribute__((ext_vector_type(8))) short bf16x8;

#define MM 16384
#define NN 512
#define KK 2048
#define OUTW 2561

#define BM7 64
#define BK 32
#define NT (KK / BK)  // 64

__device__ __forceinline__ short f2bf(float x) {
  union { __hip_bfloat16 b; short s; } u;
  u.b = __float2bfloat16(x);  // hw RNE; compiler pairs into v_cvt_pk_bf16_f32
  return u.s;
}

__device__ __forceinline__ bf16x8 cvt8(f32x4 a, f32x4 b) {
  bf16x8 r;
  r[0] = f2bf(a[0]); r[1] = f2bf(a[1]); r[2] = f2bf(a[2]); r[3] = f2bf(a[3]);
  r[4] = f2bf(b[0]); r[5] = f2bf(b[1]); r[6] = f2bf(b[2]); r[7] = f2bf(b[3]);
  return r;
}

// ---------------- prep: P [K][N] f32 -> Bt [N][K] bf16 ----------------
__global__ __launch_bounds__(256) void prep_b(const float* __restrict__ P, short* __restrict__ Bt) {
  __shared__ float ts[64][65];
  const int tid = threadIdx.x;
  const int k0 = (blockIdx.x >> 3) * 64;  // 32 k-blocks
  const int n0 = (blockIdx.x & 7) * 64;   // 8 n-blocks
#pragma unroll
  for (int j = 0; j < 16; ++j) {
    int idx = j * 256 + tid;
    int kr = idx >> 6, nc = idx & 63;
    ts[kr][nc] = P[(size_t)(k0 + kr) * NN + n0 + nc];
  }
  __syncthreads();
#pragma unroll
  for (int j = 0; j < 16; ++j) {
    int idx = j * 256 + tid;
    int nr = idx >> 6, kc = idx & 63;
    Bt[(size_t)(n0 + nr) * KK + k0 + kc] = f2bf(ts[kc][nr]);
  }
}

// ---------------- GEMM: no-LDS, no-barrier, direct-register fragments ----------------
// Wave w: rows m0 + (w>>2)*32 .. +32 (2 fragments), cols (w&3)*128 .. +128 (8 fragments).
// MFMA operand layout (verified rounds 1-6): lane holds Op[idx = lane&15][k = (lane>>4)*8 ..+8],
// which is 16B contiguous in both X (f32, 32B) and Bt (bf16, 16B) -> plain dwordx4 loads.
// B (2 MB) is L2-resident; A streams from X via L2/L3. Static 2-slot prefetch, no runtime
// indexing of register arrays (rule #20).
__global__ __launch_bounds__(512, 2) void gemm7(const float* __restrict__ X,
                                                const short* __restrict__ Bt,
                                                float* __restrict__ out) {
  const int tid = threadIdx.x;
  const int wid = tid >> 6, lane = tid & 63;
  const int lrow = lane & 15, kh = lane >> 4;
  const int wr = wid >> 2, wc = wid & 3;  // 2 row-groups x 4 col-groups

  const int m0 = blockIdx.x * BM7;  // grid 256

  const float* aP0 = X + (size_t)(m0 + wr * 32 + lrow) * KK + kh * 8;
  const float* aP1 = aP0 + (size_t)16 * KK;
  const short* bP[8];
#pragma unroll
  for (int n = 0; n < 8; ++n)
    bP[n] = Bt + (size_t)(wc * 128 + n * 16 + lrow) * KK + kh * 8;

  f32x4 acc[2][8];
#pragma unroll
  for (int m = 0; m < 2; ++m)
#pragma unroll
    for (int n = 0; n < 8; ++n) acc[m][n] = (f32x4)0.0f;

  // two static prefetch slots (even/odd t)
  f32x4 a0m0l, a0m0h, a0m1l, a0m1h;   // slot 0 A regs
  f32x4 a1m0l, a1m0h, a1m1l, a1m1h;   // slot 1 A regs
  bf16x8 b0[8], b1[8];

  // prologue: A(0)->slot0, A(1)->slot1, B(0)->slot0
  a0m0l = *(const f32x4*)(aP0);      a0m0h = *(const f32x4*)(aP0 + 4);
  a0m1l = *(const f32x4*)(aP1);      a0m1h = *(const f32x4*)(aP1 + 4);
  a1m0l = *(const f32x4*)(aP0 + BK); a1m0h = *(const f32x4*)(aP0 + BK + 4);
  a1m1l = *(const f32x4*)(aP1 + BK); a1m1h = *(const f32x4*)(aP1 + BK + 4);
#pragma unroll
  for (int n = 0; n < 8; ++n) b0[n] = *(const bf16x8*)(bP[n]);

  for (int t = 0; t < NT; t += 2) {
    // ---- even tile t: consume slot 0 ----
    {
      // prefetch B(t+1) -> slot 1
#pragma unroll
      for (int n = 0; n < 8; ++n) b1[n] = *(const bf16x8*)(bP[n] + (size_t)(t + 1) * BK);
      bf16x8 af0 = cvt8(a0m0l, a0m0h);
      bf16x8 af1 = cvt8(a0m1l, a0m1h);
      // prefetch A(t+2) -> slot 0 (clamped; redundant at tail, always in-bounds)
      {
        size_t toff = (size_t)((t + 2 < NT) ? t + 2 : NT - 1) * BK;
        a0m0l = *(const f32x4*)(aP0 + toff); a0m0h = *(const f32x4*)(aP0 + toff + 4);
        a0m1l = *(const f32x4*)(aP1 + toff); a0m1h = *(const f32x4*)(aP1 + toff + 4);
      }
#pragma unroll
      for (int n = 0; n < 8; ++n)
        acc[0][n] = __builtin_amdgcn_mfma_f32_16x16x32_bf16(af0, b0[n], acc[0][n], 0, 0, 0);
#pragma unroll
      for (int n = 0; n < 8; ++n)
        acc[1][n] = __builtin_amdgcn_mfma_f32_16x16x32_bf16(af1, b0[n], acc[1][n], 0, 0, 0);
    }
    // ---- odd tile t+1: consume slot 1 ----
    {
      // prefetch B(t+2) -> slot 0 (clamped at tail)
      size_t bo = (size_t)((t + 2 < NT) ? t + 2 : NT - 1) * BK;
#pragma unroll
      for (int n = 0; n < 8; ++n) b0[n] = *(const bf16x8*)(bP[n] + bo);
      bf16x8 af0 = cvt8(a1m0l, a1m0h);
      bf16x8 af1 = cvt8(a1m1l, a1m1h);
      // prefetch A(t+3) -> slot 1 (clamped)
      {
        size_t toff = (size_t)((t + 3 < NT) ? t + 3 : NT - 1) * BK;
        a1m0l = *(const f32x4*)(aP0 + toff); a1m0h = *(const f32x4*)(aP0 + toff + 4);
        a1m1l = *(const f32x4*)(aP1 + toff); a1m1h = *(const f32x4*)(aP1 + toff + 4);
      }
#pragma unroll
      for (int n = 0; n < 8; ++n)
        acc[0][n] = __builtin_amdgcn_mfma_f32_16x16x32_bf16(af0, b1[n], acc[0][n], 0, 0, 0);
#pragma unroll
      for (int n = 0; n < 8; ++n)
        acc[1][n] = __builtin_amdgcn_mfma_f32_16x16x32_bf16(af1, b1[n], acc[1][n], 0, 0, 0);
    }
  }

  // ---- write Xp into p1 (C/D layout: col = lane&15, row = (lane>>4)*4 + reg) ----
#pragma unroll
  for (int m = 0; m < 2; ++m)
#pragma unroll
    for (int n = 0; n < 8; ++n)
#pragma unroll
      for (int r = 0; r < 4; ++r) {
        int row = m0 + wr * 32 + m * 16 + kh * 4 + r;
        int col = wc * 128 + n * 16 + lrow;
        out[(size_t)row * OUTW + 1 + col] = acc[m][n][r];
      }
}

// ---------------- epilogue: expand features from p1 ----------------
__global__ __launch_bounds__(512) void epi_k(float* __restrict__ out) {
  const int r = blockIdx.x;
  const int c = threadIdx.x;  // 0..511
  float* row = out + (size_t)r * OUTW;
  __shared__ float s[NN];
  float xp = row[1 + c];
  s[c] = xp;
  __syncthreads();
  float p2 = xp * xp;
  float p3 = p2 * xp;
  float sq = sqrtf(fabsf(xp) + 1e-8f);
  float pr = (c < 511) ? s[0] * s[c + 1] : s[1] * s[2];
  if (c == 0) row[0] = 1.0f;
  row[513 + c] = p2;
  row[1025 + c] = p3;
  row[1537 + c] = pr;
  row[2049 + c] = sq;
}

// ---------------- fallback (no workspace): round-1 path ----------------
#define FBM 128
#define FBN 128
#define FPAD 40

__global__ __launch_bounds__(256) void gemm_k(const float* __restrict__ A,
                                              const float* __restrict__ B,
                                              float* __restrict__ out) {
  __shared__ __align__(16) short Asf[FBM][FPAD];
  __shared__ __align__(16) short Bsf[FBN][FPAD];
  const int tid = threadIdx.x;
  const int bx = blockIdx.x;
  const int m0 = (bx >> 2) * FBM;
  const int n0 = (bx & 3) * FBN;
  const int wid = tid >> 6, lane = tid & 63;
  const int wr = wid >> 1, wc = wid & 1;
  const int lrow = lane & 15, kh = lane >> 4;
  f32x4 acc[4][4];
#pragma unroll
  for (int i = 0; i < 4; i++)
#pragma unroll
    for (int j = 0; j < 4; j++) acc[i][j] = (f32x4)0.0f;
  for (int k0 = 0; k0 < KK; k0 += BK) {
#pragma unroll
    for (int i = 0; i < 4; i++) {
      int fid = i * 256 + tid;
      int ar = fid >> 3, ac = (fid & 7) << 2;
      f32x4 v = *(const f32x4*)(A + (size_t)(m0 + ar) * KK + (k0 + ac));
      short h0 = f2bf(v[0]), h1 = f2bf(v[1]), h2 = f2bf(v[2]), h3 = f2bf(v[3]);
      Asf[ar][ac] = h0; Asf[ar][ac + 1] = h1; Asf[ar][ac + 2] = h2; Asf[ar][ac + 3] = h3;
    }
#pragma unroll
    for (int i = 0; i < 4; i++) {
      int fid = i * 256 + tid;
      int br = fid >> 5, bc = (fid & 31) << 2;
      f32x4 v = *(const f32x4*)(B + (size_t)(k0 + br) * NN + (n0 + bc));
#pragma unroll
      for (int j = 0; j < 4; j++) Bsf[bc + j][br] = f2bf(v[j]);
    }
    __syncthreads();
    bf16x8 af[4], bf[4];
#pragma unroll
    for (int m = 0; m < 4; m++) af[m] = *(const bf16x8*)&Asf[wr * 64 + m * 16 + lrow][kh * 8];
#pragma unroll
    for (int n = 0; n < 4; n++) bf[n] = *(const bf16x8*)&Bsf[wc * 64 + n * 16 + lrow][kh * 8];
#pragma unroll
    for (int m = 0; m < 4; m++)
#pragma unroll
      for (int n = 0; n < 4; n++)
        acc[m][n] = __builtin_amdgcn_mfma_f32_16x16x32_bf16(af[m], bf[n], acc[m][n], 0, 0, 0);
    __syncthreads();
  }
#pragma unroll
  for (int m = 0; m < 4; m++)
#pragma unroll
    for (int n = 0; n < 4; n++)
#pragma unroll
      for (int r = 0; r < 4; r++) {
        int row = m0 + wr * 64 + m * 16 + kh * 4 + r;
        int col = n0 + wc * 64 + n * 16 + lrow;
        out[(size_t)row * OUTW + 1 + col] = acc[m][n][r];
      }
}

extern "C" void kernel_launch(void* const* d_in, const int* in_sizes, int n_in,
                              void* d_out, int out_size, void* d_ws, size_t ws_size,
                              hipStream_t stream) {
  const float* X = (const float*)d_in[0];
  const float* P = (const float*)d_in[1];
  float* out = (float*)d_out;
  (void)in_sizes; (void)n_in; (void)out_size;

  if (ws_size >= (size_t)NN * KK * sizeof(short)) {
    short* Bt = (short*)d_ws;
    prep_b<<<dim3(256), dim3(256), 0, stream>>>(P, Bt);
    gemm7<<<dim3(MM / BM7), dim3(512), 0, stream>>>(X, Bt, out);
  } else {
    gemm_k<<<dim3(512), dim3(256), 0, stream>>>(X, P, out);
  }
  epi_k<<<dim3(MM), dim3(512), 0, stream>>>(out);
}

// Round 8
// 142.220 us; speedup vs baseline: 1.5545x; 1.5545x over previous
//
#include <hip/hip_runtime.h>
#include <hip/hip_bf16.h>
#include <math.h>

// Polynomial feature map: Xp = X @ P; out = [bias | Xp | Xp^2 | Xp^3 | pairs | sqrt(|Xp|+eps)]
// X: [16384, 2048] f32, P: [2048, 512] f32, out: [16384, 2561] f32.
// pairs (triu k=1, first 512): c<511 -> Xp[:,0]*Xp[:,c+1]; c==511 -> Xp[:,1]*Xp[:,2]
//
// Path: prep_b (P -> Bt bf16 in ws) ; gemm8 = r4's proven 128x128 structure with
// SPLIT-K=2 (grid 1024 -> 4 blocks/CU for latency fill): k-half 0 writes partial
// Xp into the p1 region, k-half 1 into the p2 region (epi overwrites it anyway);
// epi2_k sums the partials and expands all feature regions.

typedef __attribute__((ext_vector_type(4))) float f32x4;
typedef __attribute__((ext_vector_type(8))) short bf16x8;

#define MM 16384
#define NN 512
#define KK 2048
#define OUTW 2561

#define BM 128
#define BN 128
#define BK 32
#define KH (KK / 2)       // 1024 per k-slice
#define NT2 (KH / BK)     // 32 steps

__device__ __forceinline__ short f2bf(float x) {
  union { __hip_bfloat16 b; short s; } u;
  u.b = __float2bfloat16(x);  // hw RNE; compiler pairs into v_cvt_pk_bf16_f32
  return u.s;
}

__device__ __forceinline__ bf16x8 cvt8(f32x4 a, f32x4 b) {
  bf16x8 r;
  r[0] = f2bf(a[0]); r[1] = f2bf(a[1]); r[2] = f2bf(a[2]); r[3] = f2bf(a[3]);
  r[4] = f2bf(b[0]); r[5] = f2bf(b[1]); r[6] = f2bf(b[2]); r[7] = f2bf(b[3]);
  return r;
}

__device__ __forceinline__ void gl_lds16(const void* g, void* l) {
  __builtin_amdgcn_global_load_lds((const __attribute__((address_space(1))) unsigned int*)g,
                                   (__attribute__((address_space(3))) unsigned int*)l, 16, 0, 0);
}

// ---------------- prep: P [K][N] f32 -> Bt [N][K] bf16 ----------------
__global__ __launch_bounds__(256) void prep_b(const float* __restrict__ P, short* __restrict__ Bt) {
  __shared__ float ts[64][65];
  const int tid = threadIdx.x;
  const int k0 = (blockIdx.x >> 3) * 64;  // 32 k-blocks
  const int n0 = (blockIdx.x & 7) * 64;   // 8 n-blocks
#pragma unroll
  for (int j = 0; j < 16; ++j) {
    int idx = j * 256 + tid;
    int kr = idx >> 6, nc = idx & 63;
    ts[kr][nc] = P[(size_t)(k0 + kr) * NN + n0 + nc];
  }
  __syncthreads();
#pragma unroll
  for (int j = 0; j < 16; ++j) {
    int idx = j * 256 + tid;
    int nr = idx >> 6, kc = idx & 63;
    Bt[(size_t)(n0 + nr) * KK + k0 + kc] = f2bf(ts[kc][nr]);
  }
}

// ---------------- GEMM: r4 structure + split-K=2 ----------------
// LDS tiles [row][32 bf16] (64B rows, 4x 16B slots), slot' = slot ^ ((row>>1)&3)
// -- measured 0 bank conflicts (rounds 3/4/6). B staged by global_load_lds (linear
// dest); swizzle realized by permuting the per-lane GLOBAL source k-slot (rule #21).
// k-slice ks covers K columns [ks*1024, ks*1024+1024); partial Xp written to
// out columns [1 + ks*512 .. 1 + ks*512 + 512) (p1 / p2 regions).
__global__ __launch_bounds__(256) void gemm8(const float* __restrict__ X,
                                             const short* __restrict__ Bt,
                                             float* __restrict__ out) {
  __shared__ short As[2][BM * BK];   // 8 KB each
  __shared__ short Bs[2][BN * BK];   // 8 KB each

  const int tid = threadIdx.x;
  const int wid = tid >> 6, lane = tid & 63;
  const int lrow = lane & 15, kh = lane >> 4;
  const int wr = wid >> 1, wc = wid & 1;  // 2x2 wave grid; wave tile 64 x 64

  // XCD-bijective swizzle over 1024 blocks (1024%8==0). s<512 -> ks=0 (XCDs 0-3),
  // s>=512 -> ks=1 (XCDs 4-7): each XCD's K-half of Bt (1 MB) fits its private L2.
  const int bid = blockIdx.x;
  const int s = (bid & 7) * 128 + (bid >> 3);
  const int ks = s >> 9;
  const int tile = s & 511;
  const int m0 = (tile >> 2) * BM;   // 128 row-blocks
  const int n0 = (tile & 3) * BN;    // 4 col-blocks (consecutive tiles share A rows)
  const int kb = ks * KH;

  // A staging: sub-iter j in {0,1}: row = j*64 + (tid>>2), 8 floats at k = (tid&3)*8
  const int ar0 = tid >> 2, akq = tid & 3;
  const float* aG = X + (size_t)(m0 + ar0) * KK + kb + akq * 8;
  int aoff[2];
#pragma unroll
  for (int j = 0; j < 2; ++j) {
    int row = j * 64 + ar0;
    aoff[j] = row * 32 + ((akq ^ ((row >> 1) & 3)) << 3);  // shorts (16B slot)
  }

  // B staging: 2 wave-loads/wave; load p covers B-rows (p*4+wid)*16 .. +15
  const int kd = (lane & 3) ^ ((lane >> 3) & 3);  // pre-swizzled source k-slot
  const short* bG[2];
  int bOff[2];
#pragma unroll
  for (int p = 0; p < 2; ++p) {
    int R0 = (p * 4 + wid) * 16;
    bOff[p] = R0 * 32;  // linear dest (shorts); hw adds lane*16B
    bG[p] = Bt + (size_t)(n0 + R0 + (lane >> 2)) * KK + kb + kd * 8;
  }

  f32x4 acc[4][4];
#pragma unroll
  for (int m = 0; m < 4; ++m)
#pragma unroll
    for (int n = 0; n < 4; ++n) acc[m][n] = (f32x4)0.0f;

  // ---- prologue: stage tile 0, prefetch A regs for tile 1 ----
#pragma unroll
  for (int p = 0; p < 2; ++p) gl_lds16(bG[p], &Bs[0][bOff[p]]);
  f32x4 a0 = *(const f32x4*)aG;
  f32x4 a1 = *(const f32x4*)(aG + 4);
  f32x4 a2 = *(const f32x4*)(aG + (size_t)64 * KK);
  f32x4 a3 = *(const f32x4*)(aG + (size_t)64 * KK + 4);
  *(bf16x8*)&As[0][aoff[0]] = cvt8(a0, a1);
  *(bf16x8*)&As[0][aoff[1]] = cvt8(a2, a3);
  a0 = *(const f32x4*)(aG + BK);
  a1 = *(const f32x4*)(aG + BK + 4);
  a2 = *(const f32x4*)(aG + (size_t)64 * KK + BK);
  a3 = *(const f32x4*)(aG + (size_t)64 * KK + BK + 4);
  __syncthreads();

  int cur = 0;
  for (int t = 0; t < NT2; ++t) {
    if (t + 1 < NT2) {
      // issue next-tile staging BEFORE compute (hidden under MFMA; drained at barrier)
#pragma unroll
      for (int p = 0; p < 2; ++p) gl_lds16(bG[p] + (size_t)(t + 1) * BK, &Bs[cur ^ 1][bOff[p]]);
      *(bf16x8*)&As[cur ^ 1][aoff[0]] = cvt8(a0, a1);
      *(bf16x8*)&As[cur ^ 1][aoff[1]] = cvt8(a2, a3);
      int t2 = (t + 2 < NT2) ? t + 2 : t;  // clamp; redundant but in-bounds at tail
      const float* ap = aG + (size_t)t2 * BK;
      a0 = *(const f32x4*)ap;
      a1 = *(const f32x4*)(ap + 4);
      a2 = *(const f32x4*)(ap + (size_t)64 * KK);
      a3 = *(const f32x4*)(ap + (size_t)64 * KK + 4);
    }
    // ---- fragments + MFMA from buf[cur]: 8 ds_read_b128, 16 MFMA ----
    const int sw = (lrow >> 1) & 3;
    bf16x8 af[4], bfr[4];
#pragma unroll
    for (int m = 0; m < 4; ++m) {
      int r = wr * 64 + m * 16 + lrow;
      af[m] = *(const bf16x8*)&As[cur][r * 32 + ((kh ^ sw) << 3)];
    }
#pragma unroll
    for (int n = 0; n < 4; ++n) {
      int r = wc * 64 + n * 16 + lrow;
      bfr[n] = *(const bf16x8*)&Bs[cur][r * 32 + ((kh ^ sw) << 3)];
    }
#pragma unroll
    for (int m = 0; m < 4; ++m)
#pragma unroll
      for (int n = 0; n < 4; ++n)
        acc[m][n] = __builtin_amdgcn_mfma_f32_16x16x32_bf16(af[m], bfr[n], acc[m][n], 0, 0, 0);
    __syncthreads();
    cur ^= 1;
  }

  // ---- write partial Xp into region ks (C/D layout: col = lane&15, row = kh*4 + reg) ----
#pragma unroll
  for (int m = 0; m < 4; ++m)
#pragma unroll
    for (int n = 0; n < 4; ++n)
#pragma unroll
      for (int r = 0; r < 4; ++r) {
        int row = m0 + wr * 64 + m * 16 + kh * 4 + r;
        int col = n0 + wc * 64 + n * 16 + lrow;
        out[(size_t)row * OUTW + 1 + ks * NN + col] = acc[m][n][r];
      }
}

// ---------------- epilogue: sum split-K partials, expand features ----------------
__global__ __launch_bounds__(512) void epi2_k(float* __restrict__ out) {
  const int r = blockIdx.x;
  const int c = threadIdx.x;  // 0..511
  float* row = out + (size_t)r * OUTW;
  __shared__ float s[NN];
  float xp = row[1 + c] + row[513 + c];   // partial0 (p1 region) + partial1 (p2 region)
  s[c] = xp;
  __syncthreads();
  float p2 = xp * xp;
  float p3 = p2 * xp;
  float sq = sqrtf(fabsf(xp) + 1e-8f);
  float pr = (c < 511) ? s[0] * s[c + 1] : s[1] * s[2];
  if (c == 0) row[0] = 1.0f;
  row[1 + c] = xp;
  row[513 + c] = p2;
  row[1025 + c] = p3;
  row[1537 + c] = pr;
  row[2049 + c] = sq;
}

// ---------------- fallback (no workspace): round-1 path ----------------
#define FBM 128
#define FBN 128
#define FPAD 40

__global__ __launch_bounds__(256) void gemm_k(const float* __restrict__ A,
                                              const float* __restrict__ B,
                                              float* __restrict__ out) {
  __shared__ __align__(16) short Asf[FBM][FPAD];
  __shared__ __align__(16) short Bsf[FBN][FPAD];
  const int tid = threadIdx.x;
  const int bx = blockIdx.x;
  const int m0 = (bx >> 2) * FBM;
  const int n0 = (bx & 3) * FBN;
  const int wid = tid >> 6, lane = tid & 63;
  const int wr = wid >> 1, wc = wid & 1;
  const int lrow = lane & 15, kh = lane >> 4;
  f32x4 acc[4][4];
#pragma unroll
  for (int i = 0; i < 4; i++)
#pragma unroll
    for (int j = 0; j < 4; j++) acc[i][j] = (f32x4)0.0f;
  for (int k0 = 0; k0 < KK; k0 += BK) {
#pragma unroll
    for (int i = 0; i < 4; i++) {
      int fid = i * 256 + tid;
      int ar = fid >> 3, ac = (fid & 7) << 2;
      f32x4 v = *(const f32x4*)(A + (size_t)(m0 + ar) * KK + (k0 + ac));
      short h0 = f2bf(v[0]), h1 = f2bf(v[1]), h2 = f2bf(v[2]), h3 = f2bf(v[3]);
      Asf[ar][ac] = h0; Asf[ar][ac + 1] = h1; Asf[ar][ac + 2] = h2; Asf[ar][ac + 3] = h3;
    }
#pragma unroll
    for (int i = 0; i < 4; i++) {
      int fid = i * 256 + tid;
      int br = fid >> 5, bc = (fid & 31) << 2;
      f32x4 v = *(const f32x4*)(B + (size_t)(k0 + br) * NN + (n0 + bc));
#pragma unroll
      for (int j = 0; j < 4; j++) Bsf[bc + j][br] = f2bf(v[j]);
    }
    __syncthreads();
    bf16x8 af[4], bf[4];
#pragma unroll
    for (int m = 0; m < 4; m++) af[m] = *(const bf16x8*)&Asf[wr * 64 + m * 16 + lrow][kh * 8];
#pragma unroll
    for (int n = 0; n < 4; n++) bf[n] = *(const bf16x8*)&Bsf[wc * 64 + n * 16 + lrow][kh * 8];
#pragma unroll
    for (int m = 0; m < 4; m++)
#pragma unroll
      for (int n = 0; n < 4; n++)
        acc[m][n] = __builtin_amdgcn_mfma_f32_16x16x32_bf16(af[m], bf[n], acc[m][n], 0, 0, 0);
    __syncthreads();
  }
#pragma unroll
  for (int m = 0; m < 4; m++)
#pragma unroll
    for (int n = 0; n < 4; n++)
#pragma unroll
      for (int r = 0; r < 4; r++) {
        int row = m0 + wr * 64 + m * 16 + kh * 4 + r;
        int col = n0 + wc * 64 + n * 16 + lrow;
        out[(size_t)row * OUTW + 1 + col] = acc[m][n][r];
      }
}

__global__ __launch_bounds__(512) void epi_k(float* __restrict__ out) {
  const int r = blockIdx.x;
  const int c = threadIdx.x;
  float* row = out + (size_t)r * OUTW;
  __shared__ float s[NN];
  float xp = row[1 + c];
  s[c] = xp;
  __syncthreads();
  float p2 = xp * xp;
  float p3 = p2 * xp;
  float sq = sqrtf(fabsf(xp) + 1e-8f);
  float pr = (c < 511) ? s[0] * s[c + 1] : s[1] * s[2];
  if (c == 0) row[0] = 1.0f;
  row[513 + c] = p2;
  row[1025 + c] = p3;
  row[1537 + c] = pr;
  row[2049 + c] = sq;
}

extern "C" void kernel_launch(void* const* d_in, const int* in_sizes, int n_in,
                              void* d_out, int out_size, void* d_ws, size_t ws_size,
                              hipStream_t stream) {
  const float* X = (const float*)d_in[0];
  const float* P = (const float*)d_in[1];
  float* out = (float*)d_out;
  (void)in_sizes; (void)n_in; (void)out_size;

  if (ws_size >= (size_t)NN * KK * sizeof(short)) {
    short* Bt = (short*)d_ws;
    prep_b<<<dim3(256), dim3(256), 0, stream>>>(P, Bt);
    gemm8<<<dim3(1024), dim3(256), 0, stream>>>(X, Bt, out);
    epi2_k<<<dim3(MM), dim3(512), 0, stream>>>(out);
  } else {
    gemm_k<<<dim3(512), dim3(256), 0, stream>>>(X, P, out);
    epi_k<<<dim3(MM), dim3(512), 0, stream>>>(out);
  }
}

// Round 9
// 136.327 us; speedup vs baseline: 1.6217x; 1.0432x over previous
//
#include <hip/hip_runtime.h>
#include <hip/hip_bf16.h>
#include <math.h>

// Polynomial feature map: Xp = X @ P; out = [bias | Xp | Xp^2 | Xp^3 | pairs | sqrt(|Xp|+eps)]
// X: [16384, 2048] f32, P: [2048, 512] f32, out: [16384, 2561] f32.
// pairs (triu k=1, first 512): c<511 -> Xp[:,0]*Xp[:,c+1]; c==511 -> Xp[:,1]*Xp[:,2]
//
// Fast path: prep_b (P -> Bt bf16) + xcvt (X -> Xb bf16), both in ws; gemm9 = m97-exact
// staging (global_load_lds only, no VALU/reg staging) + split-K=2 (grid 1024, partials
// to p1/p2 regions); epi2_k sums partials and expands features.

typedef __attribute__((ext_vector_type(4))) float f32x4;
typedef __attribute__((ext_vector_type(8))) short bf16x8;

#define MM 16384
#define NN 512
#define KK 2048
#define OUTW 2561

#define BM 128
#define BN 128
#define BK 32
#define KH (KK / 2)       // 1024 per k-slice
#define NT2 (KH / BK)     // 32 steps

__device__ __forceinline__ short f2bf(float x) {
  union { __hip_bfloat16 b; short s; } u;
  u.b = __float2bfloat16(x);  // hw RNE; compiler pairs into v_cvt_pk_bf16_f32
  return u.s;
}

__device__ __forceinline__ bf16x8 cvt8(f32x4 a, f32x4 b) {
  bf16x8 r;
  r[0] = f2bf(a[0]); r[1] = f2bf(a[1]); r[2] = f2bf(a[2]); r[3] = f2bf(a[3]);
  r[4] = f2bf(b[0]); r[5] = f2bf(b[1]); r[6] = f2bf(b[2]); r[7] = f2bf(b[3]);
  return r;
}

__device__ __forceinline__ void gl_lds16(const void* g, void* l) {
  __builtin_amdgcn_global_load_lds((const __attribute__((address_space(1))) unsigned int*)g,
                                   (__attribute__((address_space(3))) unsigned int*)l, 16, 0, 0);
}

// ---------------- prep: P [K][N] f32 -> Bt [N][K] bf16 ----------------
__global__ __launch_bounds__(256) void prep_b(const float* __restrict__ P, short* __restrict__ Bt) {
  __shared__ float ts[64][65];
  const int tid = threadIdx.x;
  const int k0 = (blockIdx.x >> 3) * 64;  // 32 k-blocks
  const int n0 = (blockIdx.x & 7) * 64;   // 8 n-blocks
#pragma unroll
  for (int j = 0; j < 16; ++j) {
    int idx = j * 256 + tid;
    int kr = idx >> 6, nc = idx & 63;
    ts[kr][nc] = P[(size_t)(k0 + kr) * NN + n0 + nc];
  }
  __syncthreads();
#pragma unroll
  for (int j = 0; j < 16; ++j) {
    int idx = j * 256 + tid;
    int nr = idx >> 6, kc = idx & 63;
    Bt[(size_t)(n0 + nr) * KK + k0 + kc] = f2bf(ts[kc][nr]);
  }
}

// ---------------- xcvt: X [M][K] f32 -> Xb [M][K] bf16 ----------------
__global__ __launch_bounds__(256) void xcvt(const float* __restrict__ X, short* __restrict__ Xb) {
  size_t i = ((size_t)blockIdx.x * 256 + threadIdx.x) * 8;  // grid covers 33.55M elems
  f32x4 a = *(const f32x4*)(X + i);
  f32x4 b = *(const f32x4*)(X + i + 4);
  *(bf16x8*)(Xb + i) = cvt8(a, b);
}

// ---------------- GEMM: m97-exact staging + split-K=2 ----------------
// LDS tiles [row][32 bf16] (64B rows, 4x 16B slots), phys slot = k-slot ^ ((row>>1)&3)
// -- measured 0 bank conflicts (rounds 3/4/6/8) on ds_read_b128 fragments. BOTH A and B
// staged by global_load_lds (linear dest = wave-uniform base + lane*16B); the swizzle is
// realized by permuting the per-lane GLOBAL source k-slot kd = (lane&3)^((lane>>3)&3)
// (rule #21). No register staging, no in-loop converts -> low VGPR -> 4 waves/SIMD.
__global__ __launch_bounds__(256, 4) void gemm9(const short* __restrict__ Xb,
                                                const short* __restrict__ Bt,
                                                float* __restrict__ out) {
  __shared__ short As[2][BM * BK];   // 8 KB each
  __shared__ short Bs[2][BN * BK];   // 8 KB each

  const int tid = threadIdx.x;
  const int wid = tid >> 6, lane = tid & 63;
  const int lrow = lane & 15, kh = lane >> 4;
  const int wr = wid >> 1, wc = wid & 1;  // 2x2 wave grid; wave tile 64 x 64

  // XCD-bijective swizzle over 1024 blocks (1024%8==0). s<512 -> ks=0 (XCDs 0-3),
  // s>=512 -> ks=1 (XCDs 4-7): each XCD's K-half of Bt (1 MB) fits its private L2.
  const int bid = blockIdx.x;
  const int s = (bid & 7) * 128 + (bid >> 3);
  const int ks = s >> 9;
  const int tile = s & 511;
  const int m0 = (tile >> 2) * BM;   // 128 row-blocks
  const int n0 = (tile & 3) * BN;    // 4 col-blocks (consecutive tiles share A rows)
  const int kb = ks * KH;

  // staging descriptors: 2 A-loads + 2 B-loads per wave; load p covers rows (p*4+wid)*16..+15
  const int kd = (lane & 3) ^ ((lane >> 3) & 3);  // pre-swizzled source k-slot
  const short* aG[2];
  const short* bG[2];
  int tOff[2];
#pragma unroll
  for (int p = 0; p < 2; ++p) {
    int R0 = (p * 4 + wid) * 16;
    tOff[p] = R0 * 32;  // linear dest (shorts); hw adds lane*16B
    aG[p] = Xb + (size_t)(m0 + R0 + (lane >> 2)) * KK + kb + kd * 8;
    bG[p] = Bt + (size_t)(n0 + R0 + (lane >> 2)) * KK + kb + kd * 8;
  }

  f32x4 acc[4][4];
#pragma unroll
  for (int m = 0; m < 4; ++m)
#pragma unroll
    for (int n = 0; n < 4; ++n) acc[m][n] = (f32x4)0.0f;

  // ---- prologue: stage tile 0 ----
#pragma unroll
  for (int p = 0; p < 2; ++p) gl_lds16(aG[p], &As[0][tOff[p]]);
#pragma unroll
  for (int p = 0; p < 2; ++p) gl_lds16(bG[p], &Bs[0][tOff[p]]);
  __syncthreads();

  int cur = 0;
  for (int t = 0; t < NT2; ++t) {
    if (t + 1 < NT2) {
      // issue next-tile staging BEFORE compute (hidden under MFMA; drained at barrier)
#pragma unroll
      for (int p = 0; p < 2; ++p) gl_lds16(aG[p] + (size_t)(t + 1) * BK, &As[cur ^ 1][tOff[p]]);
#pragma unroll
      for (int p = 0; p < 2; ++p) gl_lds16(bG[p] + (size_t)(t + 1) * BK, &Bs[cur ^ 1][tOff[p]]);
    }
    // ---- fragments + MFMA from buf[cur]: 8 ds_read_b128, 16 MFMA ----
    const int sw = (lrow >> 1) & 3;
    bf16x8 af[4], bfr[4];
#pragma unroll
    for (int m = 0; m < 4; ++m) {
      int r = wr * 64 + m * 16 + lrow;
      af[m] = *(const bf16x8*)&As[cur][r * 32 + ((kh ^ sw) << 3)];
    }
#pragma unroll
    for (int n = 0; n < 4; ++n) {
      int r = wc * 64 + n * 16 + lrow;
      bfr[n] = *(const bf16x8*)&Bs[cur][r * 32 + ((kh ^ sw) << 3)];
    }
#pragma unroll
    for (int m = 0; m < 4; ++m)
#pragma unroll
      for (int n = 0; n < 4; ++n)
        acc[m][n] = __builtin_amdgcn_mfma_f32_16x16x32_bf16(af[m], bfr[n], acc[m][n], 0, 0, 0);
    __syncthreads();
    cur ^= 1;
  }

  // ---- write partial Xp into region ks (C/D layout: col = lane&15, row = kh*4 + reg) ----
#pragma unroll
  for (int m = 0; m < 4; ++m)
#pragma unroll
    for (int n = 0; n < 4; ++n)
#pragma unroll
      for (int r = 0; r < 4; ++r) {
        int row = m0 + wr * 64 + m * 16 + kh * 4 + r;
        int col = n0 + wc * 64 + n * 16 + lrow;
        out[(size_t)row * OUTW + 1 + ks * NN + col] = acc[m][n][r];
      }
}

// ---------------- epilogue: sum split-K partials, expand features ----------------
__global__ __launch_bounds__(512) void epi2_k(float* __restrict__ out) {
  const int r = blockIdx.x;
  const int c = threadIdx.x;  // 0..511
  float* row = out + (size_t)r * OUTW;
  __shared__ float s[NN];
  float xp = row[1 + c] + row[513 + c];   // partial0 (p1 region) + partial1 (p2 region)
  s[c] = xp;
  __syncthreads();
  float p2 = xp * xp;
  float p3 = p2 * xp;
  float sq = sqrtf(fabsf(xp) + 1e-8f);
  float pr = (c < 511) ? s[0] * s[c + 1] : s[1] * s[2];
  if (c == 0) row[0] = 1.0f;
  row[1 + c] = xp;
  row[513 + c] = p2;
  row[1025 + c] = p3;
  row[1537 + c] = pr;
  row[2049 + c] = sq;
}

// ---------------- mid fallback (ws >= 2MB): round-8 gemm (reg-staged A) ----------------
__global__ __launch_bounds__(256) void gemm8(const float* __restrict__ X,
                                             const short* __restrict__ Bt,
                                             float* __restrict__ out) {
  __shared__ short As[2][BM * BK];
  __shared__ short Bs[2][BN * BK];
  const int tid = threadIdx.x;
  const int wid = tid >> 6, lane = tid & 63;
  const int lrow = lane & 15, kh = lane >> 4;
  const int wr = wid >> 1, wc = wid & 1;
  const int bid = blockIdx.x;
  const int s = (bid & 7) * 128 + (bid >> 3);
  const int ks = s >> 9;
  const int tile = s & 511;
  const int m0 = (tile >> 2) * BM;
  const int n0 = (tile & 3) * BN;
  const int kb = ks * KH;
  const int ar0 = tid >> 2, akq = tid & 3;
  const float* aG = X + (size_t)(m0 + ar0) * KK + kb + akq * 8;
  int aoff[2];
#pragma unroll
  for (int j = 0; j < 2; ++j) {
    int row = j * 64 + ar0;
    aoff[j] = row * 32 + ((akq ^ ((row >> 1) & 3)) << 3);
  }
  const int kd = (lane & 3) ^ ((lane >> 3) & 3);
  const short* bG[2];
  int bOff[2];
#pragma unroll
  for (int p = 0; p < 2; ++p) {
    int R0 = (p * 4 + wid) * 16;
    bOff[p] = R0 * 32;
    bG[p] = Bt + (size_t)(n0 + R0 + (lane >> 2)) * KK + kb + kd * 8;
  }
  f32x4 acc[4][4];
#pragma unroll
  for (int m = 0; m < 4; ++m)
#pragma unroll
    for (int n = 0; n < 4; ++n) acc[m][n] = (f32x4)0.0f;
#pragma unroll
  for (int p = 0; p < 2; ++p) gl_lds16(bG[p], &Bs[0][bOff[p]]);
  f32x4 a0 = *(const f32x4*)aG;
  f32x4 a1 = *(const f32x4*)(aG + 4);
  f32x4 a2 = *(const f32x4*)(aG + (size_t)64 * KK);
  f32x4 a3 = *(const f32x4*)(aG + (size_t)64 * KK + 4);
  *(bf16x8*)&As[0][aoff[0]] = cvt8(a0, a1);
  *(bf16x8*)&As[0][aoff[1]] = cvt8(a2, a3);
  a0 = *(const f32x4*)(aG + BK);
  a1 = *(const f32x4*)(aG + BK + 4);
  a2 = *(const f32x4*)(aG + (size_t)64 * KK + BK);
  a3 = *(const f32x4*)(aG + (size_t)64 * KK + BK + 4);
  __syncthreads();
  int cur = 0;
  for (int t = 0; t < NT2; ++t) {
    if (t + 1 < NT2) {
#pragma unroll
      for (int p = 0; p < 2; ++p) gl_lds16(bG[p] + (size_t)(t + 1) * BK, &Bs[cur ^ 1][bOff[p]]);
      *(bf16x8*)&As[cur ^ 1][aoff[0]] = cvt8(a0, a1);
      *(bf16x8*)&As[cur ^ 1][aoff[1]] = cvt8(a2, a3);
      int t2 = (t + 2 < NT2) ? t + 2 : t;
      const float* ap = aG + (size_t)t2 * BK;
      a0 = *(const f32x4*)ap;
      a1 = *(const f32x4*)(ap + 4);
      a2 = *(const f32x4*)(ap + (size_t)64 * KK);
      a3 = *(const f32x4*)(ap + (size_t)64 * KK + 4);
    }
    const int sw = (lrow >> 1) & 3;
    bf16x8 af[4], bfr[4];
#pragma unroll
    for (int m = 0; m < 4; ++m) {
      int r = wr * 64 + m * 16 + lrow;
      af[m] = *(const bf16x8*)&As[cur][r * 32 + ((kh ^ sw) << 3)];
    }
#pragma unroll
    for (int n = 0; n < 4; ++n) {
      int r = wc * 64 + n * 16 + lrow;
      bfr[n] = *(const bf16x8*)&Bs[cur][r * 32 + ((kh ^ sw) << 3)];
    }
#pragma unroll
    for (int m = 0; m < 4; ++m)
#pragma unroll
      for (int n = 0; n < 4; ++n)
        acc[m][n] = __builtin_amdgcn_mfma_f32_16x16x32_bf16(af[m], bfr[n], acc[m][n], 0, 0, 0);
    __syncthreads();
    cur ^= 1;
  }
#pragma unroll
  for (int m = 0; m < 4; ++m)
#pragma unroll
    for (int n = 0; n < 4; ++n)
#pragma unroll
      for (int r = 0; r < 4; ++r) {
        int row = m0 + wr * 64 + m * 16 + kh * 4 + r;
        int col = n0 + wc * 64 + n * 16 + lrow;
        out[(size_t)row * OUTW + 1 + ks * NN + col] = acc[m][n][r];
      }
}

// ---------------- last fallback (no workspace): round-1 path ----------------
#define FBM 128
#define FBN 128
#define FPAD 40

__global__ __launch_bounds__(256) void gemm_k(const float* __restrict__ A,
                                              const float* __restrict__ B,
                                              float* __restrict__ out) {
  __shared__ __align__(16) short Asf[FBM][FPAD];
  __shared__ __align__(16) short Bsf[FBN][FPAD];
  const int tid = threadIdx.x;
  const int bx = blockIdx.x;
  const int m0 = (bx >> 2) * FBM;
  const int n0 = (bx & 3) * FBN;
  const int wid = tid >> 6, lane = tid & 63;
  const int wr = wid >> 1, wc = wid & 1;
  const int lrow = lane & 15, kh = lane >> 4;
  f32x4 acc[4][4];
#pragma unroll
  for (int i = 0; i < 4; i++)
#pragma unroll
    for (int j = 0; j < 4; j++) acc[i][j] = (f32x4)0.0f;
  for (int k0 = 0; k0 < KK; k0 += BK) {
#pragma unroll
    for (int i = 0; i < 4; i++) {
      int fid = i * 256 + tid;
      int ar = fid >> 3, ac = (fid & 7) << 2;
      f32x4 v = *(const f32x4*)(A + (size_t)(m0 + ar) * KK + (k0 + ac));
      short h0 = f2bf(v[0]), h1 = f2bf(v[1]), h2 = f2bf(v[2]), h3 = f2bf(v[3]);
      Asf[ar][ac] = h0; Asf[ar][ac + 1] = h1; Asf[ar][ac + 2] = h2; Asf[ar][ac + 3] = h3;
    }
#pragma unroll
    for (int i = 0; i < 4; i++) {
      int fid = i * 256 + tid;
      int br = fid >> 5, bc = (fid & 31) << 2;
      f32x4 v = *(const f32x4*)(B + (size_t)(k0 + br) * NN + (n0 + bc));
#pragma unroll
      for (int j = 0; j < 4; j++) Bsf[bc + j][br] = f2bf(v[j]);
    }
    __syncthreads();
    bf16x8 af[4], bf[4];
#pragma unroll
    for (int m = 0; m < 4; m++) af[m] = *(const bf16x8*)&Asf[wr * 64 + m * 16 + lrow][kh * 8];
#pragma unroll
    for (int n = 0; n < 4; n++) bf[n] = *(const bf16x8*)&Bsf[wc * 64 + n * 16 + lrow][kh * 8];
#pragma unroll
    for (int m = 0; m < 4; m++)
#pragma unroll
      for (int n = 0; n < 4; n++)
        acc[m][n] = __builtin_amdgcn_mfma_f32_16x16x32_bf16(af[m], bf[n], acc[m][n], 0, 0, 0);
    __syncthreads();
  }
#pragma unroll
  for (int m = 0; m < 4; m++)
#pragma unroll
    for (int n = 0; n < 4; n++)
#pragma unroll
      for (int r = 0; r < 4; r++) {
        int row = m0 + wr * 64 + m * 16 + kh * 4 + r;
        int col = n0 + wc * 64 + n * 16 + lrow;
        out[(size_t)row * OUTW + 1 + col] = acc[m][n][r];
      }
}

__global__ __launch_bounds__(512) void epi_k(float* __restrict__ out) {
  const int r = blockIdx.x;
  const int c = threadIdx.x;
  float* row = out + (size_t)r * OUTW;
  __shared__ float s[NN];
  float xp = row[1 + c];
  s[c] = xp;
  __syncthreads();
  float p2 = xp * xp;
  float p3 = p2 * xp;
  float sq = sqrtf(fabsf(xp) + 1e-8f);
  float pr = (c < 511) ? s[0] * s[c + 1] : s[1] * s[2];
  if (c == 0) row[0] = 1.0f;
  row[513 + c] = p2;
  row[1025 + c] = p3;
  row[1537 + c] = pr;
  row[2049 + c] = sq;
}

extern "C" void kernel_launch(void* const* d_in, const int* in_sizes, int n_in,
                              void* d_out, int out_size, void* d_ws, size_t ws_size,
                              hipStream_t stream) {
  const float* X = (const float*)d_in[0];
  const float* P = (const float*)d_in[1];
  float* out = (float*)d_out;
  (void)in_sizes; (void)n_in; (void)out_size;

  const size_t btBytes = (size_t)NN * KK * sizeof(short);            // 2 MB
  const size_t xbBytes = (size_t)MM * KK * sizeof(short);            // 67.1 MB

  if (ws_size >= btBytes + xbBytes) {
    short* Bt = (short*)d_ws;
    short* Xb = (short*)((char*)d_ws + btBytes);
    prep_b<<<dim3(256), dim3(256), 0, stream>>>(P, Bt);
    xcvt<<<dim3((MM * KK) / (256 * 8)), dim3(256), 0, stream>>>(X, Xb);
    gemm9<<<dim3(1024), dim3(256), 0, stream>>>(Xb, Bt, out);
    epi2_k<<<dim3(MM), dim3(512), 0, stream>>>(out);
  } else if (ws_size >= btBytes) {
    short* Bt = (short*)d_ws;
    prep_b<<<dim3(256), dim3(256), 0, stream>>>(P, Bt);
    gemm8<<<dim3(1024), dim3(256), 0, stream>>>(X, Bt, out);
    epi2_k<<<dim3(MM), dim3(512), 0, stream>>>(out);
  } else {
    gemm_k<<<dim3(512), dim3(256), 0, stream>>>(X, P, out);
    epi_k<<<dim3(MM), dim3(512), 0, stream>>>(out);
  }
}